// Round 7
// baseline (233.228 us; speedup 1.0000x reference)
//
#include <hip/hip_runtime.h>

#define B_ 2048
#define N_ 1024
#define M_ 4
#define T_ 64
#define R_ 128
#define C_ 10

typedef _Float16 half8 __attribute__((ext_vector_type(8)));
typedef _Float16 half2v __attribute__((ext_vector_type(2)));
typedef __fp16 fp16x2 __attribute__((ext_vector_type(2)));
typedef float float16v __attribute__((ext_vector_type(16)));
typedef unsigned short ushort_t;
typedef unsigned int uint_t;

__device__ __forceinline__ uint_t pk16(float a, float b) {
    fp16x2 h = __builtin_amdgcn_cvt_pkrtz(a, b);
    return __builtin_bit_cast(uint_t, h);
}

// Preprocessing: blocks [0,512) feature-map+average -> div16 (f16 pairs);
// blocks [512,832) pack w_mid into 32x32x16 MFMA A-operand fragments:
// wt[(((c*4+w)*4+m)*8+ks)*64 + lane] : 8 f16 = A[o=32w+(lane&31)][i=16ks+8*(lane>>5)+j]
// where A = W_m[o][i] = w_mid[c,i,m,o].
__global__ void k_pre(const float* __restrict__ tensor, const float* __restrict__ w_mid,
                      uint2* __restrict__ div16, uint4* __restrict__ wt) {
    if (blockIdx.x < 512) {
        int gid = blockIdx.x * 256 + threadIdx.x;    // 0 .. B*T-1
        int t = gid >> 11;
        int b = gid & 2047;
        const float4* tp = (const float4*)(tensor + b * N_ + t * 16);
        float a0 = 0.f, a1 = 0.f, a2 = 0.f, a3 = 0.f;
#pragma unroll
        for (int v = 0; v < 4; ++v) {
            float4 xv = tp[v];
            float xs[4] = {xv.x, xv.y, xv.z, xv.w};
#pragma unroll
            for (int p = 0; p < 4; ++p) {
                float ang = 1.57079632679f * xs[p];
                float s, c;
                __sincosf(ang, &s, &c);
                float c2 = c * c, s2 = s * s;
                a0 += c2 * c; a1 += c2 * s; a2 += c * s2; a3 += s2 * s;
            }
        }
        const float sc = 1.0f / 16.0f;
        uint2 o; o.x = pk16(a0 * sc, a1 * sc); o.y = pk16(a2 * sc, a3 * sc);
        div16[gid] = o;
    } else {
        int gid = (blockIdx.x - 512) * 256 + threadIdx.x;   // 0 .. 81919
        int lane = gid & 63;
        int ks = (gid >> 6) & 7;
        int m  = (gid >> 9) & 3;
        int w  = (gid >> 11) & 3;
        int c  = gid >> 13;
        int h = lane >> 5, r31 = lane & 31;
        int o = w * 32 + r31;
        ushort_t hv[8];
#pragma unroll
        for (int j = 0; j < 8; ++j) {
            int i = ks * 16 + h * 8 + j;
            float v = w_mid[((c * R_ + i) * M_ + m) * R_ + o];
            union { _Float16 hh; ushort_t s; } u; u.hh = (_Float16)v; hv[j] = u.s;
        }
        uint4 ov;
        ov.x = (uint_t)hv[0] | ((uint_t)hv[1] << 16);
        ov.y = (uint_t)hv[2] | ((uint_t)hv[3] << 16);
        ov.z = (uint_t)hv[4] | ((uint_t)hv[5] << 16);
        ov.w = (uint_t)hv[6] | ((uint_t)hv[7] << 16);
        wt[gid] = ov;
    }
}

// 64-step recurrence, per-m decomposition, 32x32x16 MFMA.
// Block = (btile 32, c), 4 waves; wave w owns o in [32w, 32w+32).
// A = W_m (registers), B = state (LDS plain f16, 16B-chunk XOR swizzle),
// D[o][b] (32x32); epilogue folds x (f32) over m and writes next state.
__global__ void __launch_bounds__(256, 2)
k_main(const uint2* __restrict__ div16, const uint4* __restrict__ wt,
       const float* __restrict__ w_first, const float* __restrict__ w_last,
       float* __restrict__ logits) {
    __shared__ __align__(16) char st[16384];     // 2 buffers x 32 b x 256 B
    __shared__ __align__(16) float xbuf[8192];   // [t][b][m] f32, 32 KB
    __shared__ float uf[128];
    __shared__ float red[256];

    const int tid = threadIdx.x;
    const int c  = blockIdx.y;
    const int b0 = blockIdx.x * 32;
    const int lane = tid & 63;
    const int w = tid >> 6;
    const int h = lane >> 5;       // k-half
    const int b31 = lane & 31;     // b (B cols) / o-row (A rows)
    const int swz = b31 & 15;

    // W fragments: 32 x uint4 = 128 regs, resident for the whole kernel.
    half8 wf[4][8];   // [m][ks]
    {
        const uint4* wb = wt + (c * 4 + w) * 2048 + lane;
#pragma unroll
        for (int m = 0; m < 4; ++m)
#pragma unroll
            for (int ks = 0; ks < 8; ++ks) {
                union { uint4 u; half8 hh; } cv;
                cv.u = wb[(m * 8 + ks) * 64];
                wf[m][ks] = cv.hh;
            }
    }

    // Stage x as f32: xbuf[t*32+r] = cvt(div16[t*B + b0 + r])
#pragma unroll
    for (int k = 0; k < 8; ++k) {
        int idx = k * 256 + tid;               // t*32 + r
        int t = idx >> 5, r = idx & 31;
        uint2 d = div16[t * B_ + b0 + r];
        half2v lo = __builtin_bit_cast(half2v, d.x);
        half2v hi = __builtin_bit_cast(half2v, d.y);
        ((float4*)xbuf)[idx] = make_float4((float)lo.x, (float)lo.y, (float)hi.x, (float)hi.y);
    }

    // Initial state: state0[b][i] = sum_m w_first[c,0,m,i] (same for all b).
    if (tid < 128) {
        float s = 0.f;
#pragma unroll
        for (int m = 0; m < 4; ++m) s += w_first[(c * 4 + m) * 128 + tid];
        union { _Float16 hh; ushort_t u; } cv; cv.hh = (_Float16)s;
        int cb = tid >> 3, off = (tid & 7) * 2;
#pragma unroll
        for (int b = 0; b < 32; ++b)
            *(ushort_t*)(st + b * 256 + ((cb ^ (b & 15)) << 4) + off) = cv.u;
    }
    __syncthreads();

    for (int t = 0; t < T_; ++t) {
        const char* rbp = st + ((t & 1) ? 8192 : 0);
        char* wbp = st + ((t & 1) ? 0 : 8192);

        float16v acc[4];
        const float16v z16 = (float16v)(0.0f);

#pragma unroll
        for (int ks = 0; ks < 8; ++ks) {
            uint4 sr = *(const uint4*)(rbp + b31 * 256 + (((2 * ks + h) ^ swz) << 4));
            half8 Bf = __builtin_bit_cast(half8, sr);
#pragma unroll
            for (int m = 0; m < 4; ++m) {
                if (ks == 0)
                    acc[m] = __builtin_amdgcn_mfma_f32_32x32x16_f16(wf[m][0], Bf, z16, 0, 0, 0);
                else
                    acc[m] = __builtin_amdgcn_mfma_f32_32x32x16_f16(wf[m][ks], Bf, acc[m], 0, 0, 0);
            }
        }

        // Epilogue: next[b][o] = sum_m x[b][m]*acc_m.
        // D layout: col=b31, row = (reg&3) + 8*(reg>>2) + 4*h; o = 32w + row.
        float4 xx = ((const float4*)xbuf)[t * 32 + b31];
#pragma unroll
        for (int g = 0; g < 4; ++g) {
            float o0 = xx.x * acc[0][4*g+0] + xx.y * acc[1][4*g+0] + xx.z * acc[2][4*g+0] + xx.w * acc[3][4*g+0];
            float o1 = xx.x * acc[0][4*g+1] + xx.y * acc[1][4*g+1] + xx.z * acc[2][4*g+1] + xx.w * acc[3][4*g+1];
            float o2 = xx.x * acc[0][4*g+2] + xx.y * acc[1][4*g+2] + xx.z * acc[2][4*g+2] + xx.w * acc[3][4*g+2];
            float o3 = xx.x * acc[0][4*g+3] + xx.y * acc[1][4*g+3] + xx.z * acc[2][4*g+3] + xx.w * acc[3][4*g+3];
            uint2 dv; dv.x = pk16(o0, o1); dv.y = pk16(o2, o3);
            // o = 32w + 8g + 4h + e  ->  chunk = 4w+g, byte offset 8h within chunk
            *(uint2*)(wbp + b31 * 256 + (((4 * w + g) ^ swz) << 4) + h * 8) = dv;
        }
        __syncthreads();
    }

    // Final contraction: logits[b,c] = sum_i state[b,i] * sum_m w_last[c,i,m].
    if (tid < 128) {
        float s = 0.f;
#pragma unroll
        for (int m = 0; m < 4; ++m) s += w_last[(c * 128 + tid) * 4 + m];
        uf[tid] = s;
    }
    __syncthreads();
    {
        int b = tid & 31, seg = tid >> 5;
        float p = 0.f;
#pragma unroll
        for (int k2 = 0; k2 < 16; ++k2) {
            int i = seg * 16 + k2;           // final state in buffer 0
            ushort_t hv = *(const ushort_t*)(st + b * 256 + (((i >> 3) ^ (b & 15)) << 4) + (i & 7) * 2);
            union { ushort_t u; _Float16 hh; } cv; cv.u = hv;
            p += (float)cv.hh * uf[i];
        }
        red[seg * 32 + b] = p;
    }
    __syncthreads();
    if (tid < 32) {
        float s = 0.f;
#pragma unroll
        for (int sg = 0; sg < 8; ++sg) s += red[sg * 32 + tid];
        logits[(b0 + tid) * C_ + c] = s;
    }
}

// Log-softmax over C=10, output FLOAT32.
__global__ void k_lsm(const float* __restrict__ logits, float* __restrict__ out) {
    int b = blockIdx.x * 256 + threadIdx.x;
    float x[C_];
    float mx = -1e30f;
#pragma unroll
    for (int c = 0; c < C_; ++c) { x[c] = logits[b * C_ + c]; mx = fmaxf(mx, x[c]); }
    float s = 0.f;
#pragma unroll
    for (int c = 0; c < C_; ++c) s += __expf(x[c] - mx);
    float lse = mx + __logf(s);
#pragma unroll
    for (int c = 0; c < C_; ++c) out[b * C_ + c] = x[c] - lse;
}

extern "C" void kernel_launch(void* const* d_in, const int* in_sizes, int n_in,
                              void* d_out, int out_size, void* d_ws, size_t ws_size,
                              hipStream_t stream) {
    const float* tensor  = (const float*)d_in[0];   // (B,N)      f32
    const float* w_first = (const float*)d_in[1];   // (C,1,M,R)  f32
    const float* w_mid   = (const float*)d_in[2];   // (C,R,M,R)  f32
    const float* w_last  = (const float*)d_in[3];   // (C,R,M,1)  f32
    char* ws = (char*)d_ws;
    uint2* div16 = (uint2*)ws;                               // 1 MiB
    uint4* wt    = (uint4*)(ws + 1048576);                   // 1.31 MB
    float* logits = (float*)(ws + 1048576 + 1310720);        // 80 KB
    float* out = (float*)d_out;                              // (B,C) f32

    k_pre<<<832, 256, 0, stream>>>(tensor, w_mid, div16, wt);
    k_main<<<dim3(64, 10), 256, 0, stream>>>(div16, wt, w_first, w_last, logits);
    k_lsm<<<8, 256, 0, stream>>>(logits, out);
}

// Round 8
// 173.736 us; speedup vs baseline: 1.3424x; 1.3424x over previous
//
#include <hip/hip_runtime.h>

#define B_ 2048
#define N_ 1024
#define M_ 4
#define T_ 64
#define R_ 128
#define C_ 10

typedef _Float16 half2v __attribute__((ext_vector_type(2)));
typedef __fp16 fp16x2 __attribute__((ext_vector_type(2)));
typedef float float16v __attribute__((ext_vector_type(16)));
typedef unsigned short ushort_t;
typedef unsigned int uint_t;

__device__ __forceinline__ uint_t pk16(float a, float b) {
    fp16x2 h = __builtin_amdgcn_cvt_pkrtz(a, b);
    return __builtin_bit_cast(uint_t, h);
}
__device__ __forceinline__ float bf8dec(unsigned char b) {
    union { ushort_t u; _Float16 h; } cv; cv.u = (ushort_t)b << 8;   // e5m2 = truncated f16
    return (float)cv.h;
}

// Preprocessing: blocks [0,512) feature-map+average -> div16 (f16 pairs);
// blocks [512,832) pack w_mid into 32x32x16 bf8 MFMA A-operand fragments:
// wt8[(((c*4+w)*4+m)*8+ks)*64 + lane] : 8 bf8 = A[o=32w+(lane&31)][i=16ks+8*(lane>>5)+j]
// where A = W_m[o][i] = w_mid[c,i,m,o].
__global__ void k_pre(const float* __restrict__ tensor, const float* __restrict__ w_mid,
                      uint2* __restrict__ div16, uint2* __restrict__ wt8) {
    if (blockIdx.x < 512) {
        int gid = blockIdx.x * 256 + threadIdx.x;    // 0 .. B*T-1
        int t = gid >> 11;
        int b = gid & 2047;
        const float4* tp = (const float4*)(tensor + b * N_ + t * 16);
        float a0 = 0.f, a1 = 0.f, a2 = 0.f, a3 = 0.f;
#pragma unroll
        for (int v = 0; v < 4; ++v) {
            float4 xv = tp[v];
            float xs[4] = {xv.x, xv.y, xv.z, xv.w};
#pragma unroll
            for (int p = 0; p < 4; ++p) {
                float ang = 1.57079632679f * xs[p];
                float s, c;
                __sincosf(ang, &s, &c);
                float c2 = c * c, s2 = s * s;
                a0 += c2 * c; a1 += c2 * s; a2 += c * s2; a3 += s2 * s;
            }
        }
        const float sc = 1.0f / 16.0f;
        uint2 o; o.x = pk16(a0 * sc, a1 * sc); o.y = pk16(a2 * sc, a3 * sc);
        div16[gid] = o;
    } else {
        int gid = (blockIdx.x - 512) * 256 + threadIdx.x;   // 0 .. 81919
        int lane = gid & 63;
        int ks = (gid >> 6) & 7;
        int m  = (gid >> 9) & 3;
        int w  = (gid >> 11) & 3;
        int c  = gid >> 13;
        int h = lane >> 5, r31 = lane & 31;
        int o = w * 32 + r31;
        float v[8];
#pragma unroll
        for (int j = 0; j < 8; ++j) {
            int i = ks * 16 + h * 8 + j;
            v[j] = w_mid[((c * R_ + i) * M_ + m) * R_ + o];
        }
        int d0 = __builtin_amdgcn_cvt_pk_bf8_f32(v[0], v[1], 0, false);
        d0     = __builtin_amdgcn_cvt_pk_bf8_f32(v[2], v[3], d0, true);
        int d1 = __builtin_amdgcn_cvt_pk_bf8_f32(v[4], v[5], 0, false);
        d1     = __builtin_amdgcn_cvt_pk_bf8_f32(v[6], v[7], d1, true);
        uint2 ov; ov.x = (uint_t)d0; ov.y = (uint_t)d1;
        wt8[gid] = ov;
    }
}

// 64-step recurrence, per-m decomposition, 32x32x16 bf8_bf8 MFMA.
// Block = (btile 32, c), 4 waves; wave w owns o in [32w, 32w+32).
// A = W_m (64 VGPRs, resident), B = state (LDS bf8, 8B-chunk XOR swizzle),
// D[o][b]; epilogue folds x (f32) over m, packs bf8, writes next state.
__global__ void __launch_bounds__(256, 3)
k_main(const uint2* __restrict__ div16, const uint2* __restrict__ wt8,
       const float* __restrict__ w_first, const float* __restrict__ w_last,
       float* __restrict__ logits) {
    __shared__ __align__(16) char st[8192];      // 2 buffers x 32 b x 128 B (bf8)
    __shared__ __align__(16) float xbuf[8192];   // [t][b][m] f32, 32 KB
    __shared__ float uf[128];
    __shared__ float red[256];

    const int tid = threadIdx.x;
    const int c  = blockIdx.y;
    const int b0 = blockIdx.x * 32;
    const int lane = tid & 63;
    const int w = tid >> 6;
    const int h = lane >> 5;       // k-half
    const int b31 = lane & 31;     // b col (B/D) == o row (A)
    const int swz = b31 & 15;

    // W fragments: 32 x uint2 = 64 VGPRs, resident for the whole kernel.
    long wf[4][8];   // [m][ks], i64 = 8 bf8
    {
        const uint2* wb = wt8 + (c * 4 + w) * 2048 + lane;
#pragma unroll
        for (int m = 0; m < 4; ++m)
#pragma unroll
            for (int ks = 0; ks < 8; ++ks)
                wf[m][ks] = __builtin_bit_cast(long, wb[(m * 8 + ks) * 64]);
    }

    // Stage x as f32: xbuf[t*32+r] = cvt(div16[t*B + b0 + r])
#pragma unroll
    for (int k = 0; k < 8; ++k) {
        int idx = k * 256 + tid;               // t*32 + r
        int t = idx >> 5, r = idx & 31;
        uint2 d = div16[t * B_ + b0 + r];
        half2v lo = __builtin_bit_cast(half2v, d.x);
        half2v hi = __builtin_bit_cast(half2v, d.y);
        ((float4*)xbuf)[idx] = make_float4((float)lo.x, (float)lo.y, (float)hi.x, (float)hi.y);
    }

    // Initial state: state0[b][i] = sum_m w_first[c,0,m,i] (same for all b).
    if (tid < 128) {
        float s = 0.f;
#pragma unroll
        for (int m = 0; m < 4; ++m) s += w_first[(c * 4 + m) * 128 + tid];
        unsigned char enc = (unsigned char)(__builtin_amdgcn_cvt_pk_bf8_f32(s, s, 0, false) & 0xff);
        int i = tid;
#pragma unroll
        for (int b = 0; b < 32; ++b)
            st[b * 128 + (((i >> 3) ^ (b & 15)) << 3) + (i & 7)] = (char)enc;
    }
    __syncthreads();

    for (int t = 0; t < T_; ++t) {
        const char* rbp = st + ((t & 1) ? 4096 : 0);
        char* wbp = st + ((t & 1) ? 0 : 4096);

        float16v acc[4];
        const float16v z16 = (float16v)(0.0f);

#pragma unroll
        for (int ks = 0; ks < 8; ++ks) {
            // B-frag: 8 bf8 = state[b31][16ks + 8h + j], chunk = 2ks+h, XOR swizzle.
            long Bf = *(const long*)(rbp + b31 * 128 + (((2 * ks + h) ^ swz) << 3));
#pragma unroll
            for (int m = 0; m < 4; ++m) {
                if (ks == 0)
                    acc[m] = __builtin_amdgcn_mfma_f32_32x32x16_bf8_bf8(wf[m][0], Bf, z16, 0, 0, 0);
                else
                    acc[m] = __builtin_amdgcn_mfma_f32_32x32x16_bf8_bf8(wf[m][ks], Bf, acc[m], 0, 0, 0);
            }
        }

        // Epilogue: next[b][o] = sum_m x[b][m]*acc_m.
        // D: col=b31, row = (reg&3) + 8*(reg>>2) + 4*h; o = 32w + row.
        float4 xx = ((const float4*)xbuf)[t * 32 + b31];
#pragma unroll
        for (int g = 0; g < 4; ++g) {
            float o0 = xx.x * acc[0][4*g+0] + xx.y * acc[1][4*g+0] + xx.z * acc[2][4*g+0] + xx.w * acc[3][4*g+0];
            float o1 = xx.x * acc[0][4*g+1] + xx.y * acc[1][4*g+1] + xx.z * acc[2][4*g+1] + xx.w * acc[3][4*g+1];
            float o2 = xx.x * acc[0][4*g+2] + xx.y * acc[1][4*g+2] + xx.z * acc[2][4*g+2] + xx.w * acc[3][4*g+2];
            float o3 = xx.x * acc[0][4*g+3] + xx.y * acc[1][4*g+3] + xx.z * acc[2][4*g+3] + xx.w * acc[3][4*g+3];
            int dv = __builtin_amdgcn_cvt_pk_bf8_f32(o0, o1, 0, false);
            dv     = __builtin_amdgcn_cvt_pk_bf8_f32(o2, o3, dv, true);
            // i = 32w + 8g + 4h + e -> chunk = 4w+g, in-chunk offset 4h, 4 bytes
            *(int*)(wbp + b31 * 128 + ((((4 * w + g) ^ swz)) << 3) + h * 4) = dv;
        }
        __syncthreads();
    }

    // Final contraction: logits[b,c] = sum_i state[b,i] * sum_m w_last[c,i,m].
    if (tid < 128) {
        float s = 0.f;
#pragma unroll
        for (int m = 0; m < 4; ++m) s += w_last[(c * 128 + tid) * 4 + m];
        uf[tid] = s;
    }
    __syncthreads();
    {
        int b = tid & 31, seg = tid >> 5;
        float p = 0.f;
#pragma unroll
        for (int k2 = 0; k2 < 16; ++k2) {
            int i = seg * 16 + k2;           // final state in buffer 0
            unsigned char hv = (unsigned char)st[b * 128 + (((i >> 3) ^ (b & 15)) << 3) + (i & 7)];
            p += bf8dec(hv) * uf[i];
        }
        red[seg * 32 + b] = p;
    }
    __syncthreads();
    if (tid < 32) {
        float s = 0.f;
#pragma unroll
        for (int sg = 0; sg < 8; ++sg) s += red[sg * 32 + tid];
        logits[(b0 + tid) * C_ + c] = s;
    }
}

// Log-softmax over C=10, output FLOAT32.
__global__ void k_lsm(const float* __restrict__ logits, float* __restrict__ out) {
    int b = blockIdx.x * 256 + threadIdx.x;
    float x[C_];
    float mx = -1e30f;
#pragma unroll
    for (int c = 0; c < C_; ++c) { x[c] = logits[b * C_ + c]; mx = fmaxf(mx, x[c]); }
    float s = 0.f;
#pragma unroll
    for (int c = 0; c < C_; ++c) s += __expf(x[c] - mx);
    float lse = mx + __logf(s);
#pragma unroll
    for (int c = 0; c < C_; ++c) out[b * C_ + c] = x[c] - lse;
}

extern "C" void kernel_launch(void* const* d_in, const int* in_sizes, int n_in,
                              void* d_out, int out_size, void* d_ws, size_t ws_size,
                              hipStream_t stream) {
    const float* tensor  = (const float*)d_in[0];   // (B,N)      f32
    const float* w_first = (const float*)d_in[1];   // (C,1,M,R)  f32
    const float* w_mid   = (const float*)d_in[2];   // (C,R,M,R)  f32
    const float* w_last  = (const float*)d_in[3];   // (C,R,M,1)  f32
    char* ws = (char*)d_ws;
    uint2* div16 = (uint2*)ws;                               // 1 MiB
    uint2* wt8   = (uint2*)(ws + 1048576);                   // 640 KB
    float* logits = (float*)(ws + 1048576 + 655360);         // 80 KB
    float* out = (float*)d_out;                              // (B,C) f32

    k_pre<<<832, 256, 0, stream>>>(tensor, w_mid, div16, wt8);
    k_main<<<dim3(64, 10), 256, 0, stream>>>(div16, wt8, w_first, w_last, logits);
    k_lsm<<<8, 256, 0, stream>>>(logits, out);
}

// Round 10
// 140.962 us; speedup vs baseline: 1.6545x; 1.2325x over previous
//
#include <hip/hip_runtime.h>

#define B_ 2048
#define N_ 1024
#define M_ 4
#define T_ 64
#define R_ 128
#define C_ 10

typedef _Float16 half2v __attribute__((ext_vector_type(2)));
typedef __fp16 fp16x2 __attribute__((ext_vector_type(2)));
typedef float float16v __attribute__((ext_vector_type(16)));
typedef int int8v __attribute__((ext_vector_type(8)));
typedef unsigned short ushort_t;
typedef unsigned int uint_t;

__device__ __forceinline__ uint_t pk16(float a, float b) {
    fp16x2 h = __builtin_amdgcn_cvt_pkrtz(a, b);
    return __builtin_bit_cast(uint_t, h);
}
__device__ __forceinline__ float bf8dec(unsigned char b) {
    union { ushort_t u; _Float16 h; } cv; cv.u = (ushort_t)b << 8;   // e5m2 = truncated f16
    return (float)cv.h;
}

// Preprocessing.
// blocks [0,512): feature-map+average -> div16 (f16 pairs).
// blocks [512,552): one block per (c,m); coalesced LDS transpose of w_mid,
// emit 32x32x64-f8f6f4 A-fragments (bf8): frag (c,w,m,ks) lane (o31,h),
// byte p = 8r+u  <->  i = 64ks + 32h + 8r + u,  value W_m[o][i] = w_mid[c,i,m,o].
__global__ void k_pre(const float* __restrict__ tensor, const float* __restrict__ w_mid,
                      uint2* __restrict__ div16, uint4* __restrict__ wtA) {
    __shared__ float wl[128 * 129];
    int tid = threadIdx.x;
    if (blockIdx.x < 512) {
        int gid = blockIdx.x * 256 + tid;            // 0 .. B*T-1
        int t = gid >> 11;
        int b = gid & 2047;
        const float4* tp = (const float4*)(tensor + b * N_ + t * 16);
        float a0 = 0.f, a1 = 0.f, a2 = 0.f, a3 = 0.f;
#pragma unroll
        for (int v = 0; v < 4; ++v) {
            float4 xv = tp[v];
            float xs[4] = {xv.x, xv.y, xv.z, xv.w};
#pragma unroll
            for (int p = 0; p < 4; ++p) {
                float ang = 1.57079632679f * xs[p];
                float s, c;
                __sincosf(ang, &s, &c);
                float c2 = c * c, s2 = s * s;
                a0 += c2 * c; a1 += c2 * s; a2 += c * s2; a3 += s2 * s;
            }
        }
        const float sc = 1.0f / 16.0f;
        uint2 o; o.x = pk16(a0 * sc, a1 * sc); o.y = pk16(a2 * sc, a3 * sc);
        div16[gid] = o;
    } else {
        int bid = blockIdx.x - 512;                  // 0..39 = (c, m)
        int c = bid >> 2, m = bid & 3;
        // Stage w_mid[c, :, m, :] -> wl[i][o] (padded), coalesced.
#pragma unroll 4
        for (int it = 0; it < 64; ++it) {
            int idx = it * 256 + tid;                // i*128 + o
            int i = idx >> 7, o = idx & 127;
            wl[i * 129 + o] = w_mid[((c * 128 + i) * 4 + m) * 128 + o];
        }
        __syncthreads();
#pragma unroll
        for (int u = 0; u < 2; ++u) {
            int unit = u * 256 + tid;                // (w, ks, lane)
            int lane = unit & 63;
            int ks = (unit >> 6) & 1;
            int w = unit >> 7;
            int h = lane >> 5, r31 = lane & 31;
            int o = w * 32 + r31;
            uint_t dw[8];
#pragma unroll
            for (int r = 0; r < 4; ++r) {
                int ib = ks * 64 + h * 32 + r * 8;
                int d0 = __builtin_amdgcn_cvt_pk_bf8_f32(wl[(ib + 0) * 129 + o], wl[(ib + 1) * 129 + o], 0, false);
                d0     = __builtin_amdgcn_cvt_pk_bf8_f32(wl[(ib + 2) * 129 + o], wl[(ib + 3) * 129 + o], d0, true);
                int d1 = __builtin_amdgcn_cvt_pk_bf8_f32(wl[(ib + 4) * 129 + o], wl[(ib + 5) * 129 + o], 0, false);
                d1     = __builtin_amdgcn_cvt_pk_bf8_f32(wl[(ib + 6) * 129 + o], wl[(ib + 7) * 129 + o], d1, true);
                dw[2 * r] = (uint_t)d0; dw[2 * r + 1] = (uint_t)d1;
            }
            int frag = ((c * 4 + w) * 8) + m * 2 + ks;
            uint4* dst = wtA + frag * 128 + lane * 2;
            dst[0] = make_uint4(dw[0], dw[1], dw[2], dw[3]);
            dst[1] = make_uint4(dw[4], dw[5], dw[6], dw[7]);
        }
    }
}

// 64-step recurrence, per-m decomposition, MX-scaled 32x32x64 bf8 MFMA (unit scales).
// Block = (btile 32, c), 4 waves; wave w owns o in [32w, 32w+32).
// A = W_m (64 VGPRs), B = state (LDS bf8, 8B-chunk XOR swizzle, byte-map matched to A),
// D[o][b]; epilogue folds x (f32) over m, packs bf8, writes next state.
__global__ void __launch_bounds__(256, 3)
k_main(const uint2* __restrict__ div16, const uint4* __restrict__ wtA,
       const float* __restrict__ w_first, const float* __restrict__ w_last,
       float* __restrict__ logits) {
    __shared__ __align__(16) char st[8192];      // 2 buffers x 32 b x 128 B (bf8)
    __shared__ __align__(16) float xbuf[8192];   // [t][b][m] f32, 32 KB
    __shared__ float uf[128];
    __shared__ float red[256];

    const int tid = threadIdx.x;
    const int c  = blockIdx.y;
    const int b0 = blockIdx.x * 32;
    const int lane = tid & 63;
    const int w = tid >> 6;
    const int h = lane >> 5;       // k-half
    const int b31 = lane & 31;     // b col (B/D) == o row (A)
    const int swz = b31 & 15;

    // W fragments: 8 x int8v = 64 VGPRs, resident.
    int8v wf[4][2];   // [m][ks]
    {
        const uint4* wb = wtA + (c * 4 + w) * 8 * 128 + lane * 2;
#pragma unroll
        for (int m = 0; m < 4; ++m)
#pragma unroll
            for (int ks = 0; ks < 2; ++ks) {
                union { uint4 q[2]; int8v v; } cv;
                cv.q[0] = wb[(m * 2 + ks) * 128 + 0];
                cv.q[1] = wb[(m * 2 + ks) * 128 + 1];
                wf[m][ks] = cv.v;
            }
    }

    // Stage x as f32: xbuf[t*32+r] = cvt(div16[t*B + b0 + r])
#pragma unroll
    for (int k = 0; k < 8; ++k) {
        int idx = k * 256 + tid;               // t*32 + r
        int t = idx >> 5, r = idx & 31;
        uint2 d = div16[t * B_ + b0 + r];
        half2v lo = __builtin_bit_cast(half2v, d.x);
        half2v hi = __builtin_bit_cast(half2v, d.y);
        ((float4*)xbuf)[idx] = make_float4((float)lo.x, (float)lo.y, (float)hi.x, (float)hi.y);
    }

    // Initial state: state0[b][i] = sum_m w_first[c,0,m,i] (same for all b).
    if (tid < 128) {
        float s = 0.f;
#pragma unroll
        for (int m = 0; m < 4; ++m) s += w_first[(c * 4 + m) * 128 + tid];
        unsigned char enc = (unsigned char)(__builtin_amdgcn_cvt_pk_bf8_f32(s, s, 0, false) & 0xff);
        int i = tid;
#pragma unroll
        for (int b = 0; b < 32; ++b)
            st[b * 128 + (((i >> 3) ^ (b & 15)) << 3) + (i & 7)] = (char)enc;
    }
    __syncthreads();

    for (int t = 0; t < T_; ++t) {
        const char* rbp = st + ((t & 1) ? 4096 : 0);
        char* wbp = st + ((t & 1) ? 0 : 4096);

        float16v acc[4];
        const float16v z16 = (float16v)(0.0f);

#pragma unroll
        for (int ks = 0; ks < 2; ++ks) {
            // B-frag: byte p=8r+u <-> i = 64ks + 32h + 8r + u (chunks XOR-swizzled).
            union { uint2 q[4]; int8v v; } bb;
#pragma unroll
            for (int r = 0; r < 4; ++r)
                bb.q[r] = *(const uint2*)(rbp + b31 * 128 + (((8 * ks + 4 * h + r) ^ swz) << 3));
#pragma unroll
            for (int m = 0; m < 4; ++m) {
                if (ks == 0)
                    acc[m] = __builtin_amdgcn_mfma_scale_f32_32x32x64_f8f6f4(
                        wf[m][0], bb.v, z16, 1, 1, 0, 127, 0, 127);
                else
                    acc[m] = __builtin_amdgcn_mfma_scale_f32_32x32x64_f8f6f4(
                        wf[m][1], bb.v, acc[m], 1, 1, 0, 127, 0, 127);
            }
        }

        // Epilogue: next[b][o] = sum_m x[b][m]*acc_m.
        // D: col=b31, row = (reg&3) + 8*(reg>>2) + 4*h; o = 32w + row.
        float4 xx = ((const float4*)xbuf)[t * 32 + b31];
#pragma unroll
        for (int g = 0; g < 4; ++g) {
            float o0 = xx.x * acc[0][4*g+0] + xx.y * acc[1][4*g+0] + xx.z * acc[2][4*g+0] + xx.w * acc[3][4*g+0];
            float o1 = xx.x * acc[0][4*g+1] + xx.y * acc[1][4*g+1] + xx.z * acc[2][4*g+1] + xx.w * acc[3][4*g+1];
            float o2 = xx.x * acc[0][4*g+2] + xx.y * acc[1][4*g+2] + xx.z * acc[2][4*g+2] + xx.w * acc[3][4*g+2];
            float o3 = xx.x * acc[0][4*g+3] + xx.y * acc[1][4*g+3] + xx.z * acc[2][4*g+3] + xx.w * acc[3][4*g+3];
            int dv = __builtin_amdgcn_cvt_pk_bf8_f32(o0, o1, 0, false);
            dv     = __builtin_amdgcn_cvt_pk_bf8_f32(o2, o3, dv, true);
            *(int*)(wbp + b31 * 128 + (((4 * w + g) ^ swz) << 3) + h * 4) = dv;
        }
        __syncthreads();
    }

    // Final contraction: logits[b,c] = sum_i state[b,i] * sum_m w_last[c,i,m].
    if (tid < 128) {
        float s = 0.f;
#pragma unroll
        for (int m = 0; m < 4; ++m) s += w_last[(c * 128 + tid) * 4 + m];
        uf[tid] = s;
    }
    __syncthreads();
    {
        int b = tid & 31, seg = tid >> 5;
        float p = 0.f;
#pragma unroll
        for (int k2 = 0; k2 < 16; ++k2) {
            int i = seg * 16 + k2;           // final state in buffer 0
            unsigned char hv = (unsigned char)st[b * 128 + (((i >> 3) ^ (b & 15)) << 3) + (i & 7)];
            p += bf8dec(hv) * uf[i];
        }
        red[seg * 32 + b] = p;
    }
    __syncthreads();
    if (tid < 32) {
        float s = 0.f;
#pragma unroll
        for (int sg = 0; sg < 8; ++sg) s += red[sg * 32 + tid];
        logits[(b0 + tid) * C_ + c] = s;
    }
}

// Log-softmax over C=10, output FLOAT32.
__global__ void k_lsm(const float* __restrict__ logits, float* __restrict__ out) {
    int b = blockIdx.x * 256 + threadIdx.x;
    float x[C_];
    float mx = -1e30f;
#pragma unroll
    for (int c = 0; c < C_; ++c) { x[c] = logits[b * C_ + c]; mx = fmaxf(mx, x[c]); }
    float s = 0.f;
#pragma unroll
    for (int c = 0; c < C_; ++c) s += __expf(x[c] - mx);
    float lse = mx + __logf(s);
#pragma unroll
    for (int c = 0; c < C_; ++c) out[b * C_ + c] = x[c] - lse;
}

extern "C" void kernel_launch(void* const* d_in, const int* in_sizes, int n_in,
                              void* d_out, int out_size, void* d_ws, size_t ws_size,
                              hipStream_t stream) {
    const float* tensor  = (const float*)d_in[0];   // (B,N)      f32
    const float* w_first = (const float*)d_in[1];   // (C,1,M,R)  f32
    const float* w_mid   = (const float*)d_in[2];   // (C,R,M,R)  f32
    const float* w_last  = (const float*)d_in[3];   // (C,R,M,1)  f32
    char* ws = (char*)d_ws;
    uint2* div16 = (uint2*)ws;                               // 1 MiB
    uint4* wtA   = (uint4*)(ws + 1048576);                   // 640 KB
    float* logits = (float*)(ws + 1048576 + 655360);         // 80 KB
    float* out = (float*)d_out;                              // (B,C) f32

    k_pre<<<552, 256, 0, stream>>>(tensor, w_mid, div16, wtA);
    k_main<<<dim3(64, 10), 256, 0, stream>>>(div16, wtA, w_first, w_last, logits);
    k_lsm<<<8, 256, 0, stream>>>(logits, out);
}